// Round 12
// baseline (446.867 us; speedup 1.0000x reference)
//
#include <hip/hip_runtime.h>
#include <hip/hip_bf16.h>

#define NN 100000
#define EE 1600000
#define HALFN 50000

typedef __attribute__((ext_vector_type(8))) short short8;
typedef __attribute__((ext_vector_type(4))) float f32x4;

__device__ __forceinline__ unsigned short f2bfu(float f) {
    __hip_bfloat16 h = __float2bfloat16(f);
    return *reinterpret_cast<unsigned short*>(&h);
}
__device__ __forceinline__ float bf2f(unsigned short u) {
    return __uint_as_float((unsigned int)u << 16);
}

// ---------------- workspace layout (bytes) ----------------
// WCT 0 (49152) | BC 49152 | Z0 65536 (12.8e6) | YA 12865536 ((NN+1)*128)
// YB 25678592 | DINV 38491648 | CNT 38891648 | PTR 39291648 | BSUM 39691776
// PTR2 39693824 | CROW 40093952 (6.4e6) -> total ~46.5 MB
// y-state = dinv*z, rows padded to 64 bf16 = one 128B line; row NN = zeros (mask row)

__global__ void wct_kernel(const float* __restrict__ W1, const float* __restrict__ W2,
                           const float* __restrict__ b1, short* __restrict__ WcT,
                           float* __restrict__ bc) {
    int t = blockIdx.x * 256 + threadIdx.x;
    if (t < 48 * 512) {
        int j = t >> 9, k = t & 511;
        float s = 0.f;
        if (j < 40)
            for (int i = 0; i < 128; ++i) s = fmaf(W1[k * 128 + i], W2[i * 40 + j], s);
        WcT[j * 512 + k] = (short)f2bfu(s);
    } else if (t < 48 * 512 + 48) {
        int j = t - 48 * 512;
        float s = 0.f;
        if (j < 40)
            for (int i = 0; i < 128; ++i) s = fmaf(b1[i], W2[i * 40 + j], s);
        bc[j] = s;
    }
}

// zero the mask row (row NN) of both y buffers
__global__ void padzero_kernel(unsigned short* __restrict__ ya,
                               unsigned short* __restrict__ yb) {
    int t = threadIdx.x;
    if (t < 64) ya[(size_t)NN * 64 + t] = 0;
    else if (t < 128) yb[(size_t)NN * 64 + (t - 64)] = 0;
}

// z0 = bf16( x @ Wc + bc ); y0 = bf16( dinv * z0 ).  Rows padded to 64.
__global__ __launch_bounds__(256) void gemm_z0(const float* __restrict__ x,
                                               const short* __restrict__ WcT,
                                               const float* __restrict__ bc,
                                               const float* __restrict__ dinvp,
                                               unsigned short* __restrict__ z0,
                                               unsigned short* __restrict__ y0) {
    const int tid = threadIdx.x;
    const int lane = tid & 63;
    const int wave = tid >> 6;
    const int rbase = blockIdx.x * 64 + wave * 16;
    const int row = rbase + (lane & 15);
    const int kc = lane >> 4;
    const bool rok = row < NN;

    f32x4 acc0 = {0.f, 0.f, 0.f, 0.f};
    f32x4 acc1 = {0.f, 0.f, 0.f, 0.f};
    f32x4 acc2 = {0.f, 0.f, 0.f, 0.f};

    const float* xrow = x + (size_t)row * 512 + kc * 8;
    const short* bp0 = WcT + (size_t)(lane & 15) * 512 + kc * 8;
    const short* bp1 = bp0 + 16 * 512;
    const short* bp2 = bp0 + 32 * 512;

    for (int k0 = 0; k0 < 512; k0 += 32) {
        float4 p0 = {0.f, 0.f, 0.f, 0.f}, p1 = {0.f, 0.f, 0.f, 0.f};
        if (rok) {
            p0 = *reinterpret_cast<const float4*>(xrow + k0);
            p1 = *reinterpret_cast<const float4*>(xrow + k0 + 4);
        }
        short8 a;
        a[0] = (short)f2bfu(p0.x); a[1] = (short)f2bfu(p0.y);
        a[2] = (short)f2bfu(p0.z); a[3] = (short)f2bfu(p0.w);
        a[4] = (short)f2bfu(p1.x); a[5] = (short)f2bfu(p1.y);
        a[6] = (short)f2bfu(p1.z); a[7] = (short)f2bfu(p1.w);
        short8 b0 = *reinterpret_cast<const short8*>(bp0 + k0);
        short8 b1 = *reinterpret_cast<const short8*>(bp1 + k0);
        short8 b2 = *reinterpret_cast<const short8*>(bp2 + k0);
        acc0 = __builtin_amdgcn_mfma_f32_16x16x32_bf16(a, b0, acc0, 0, 0, 0);
        acc1 = __builtin_amdgcn_mfma_f32_16x16x32_bf16(a, b1, acc1, 0, 0, 0);
        acc2 = __builtin_amdgcn_mfma_f32_16x16x32_bf16(a, b2, acc2, 0, 0, 0);
    }

    const int cb = lane & 15;
    const int rr = rbase + (lane >> 4) * 4;
#pragma unroll
    for (int q = 0; q < 4; ++q) {
        int r = rr + q;
        if (r < NN) {
            float dc = dinvp[r];
            float v0 = acc0[q] + bc[cb];
            float v1 = acc1[q] + bc[cb + 16];
            float v2 = acc2[q] + bc[cb + 32];
            z0[(size_t)r * 64 + cb] = f2bfu(v0);
            z0[(size_t)r * 64 + cb + 16] = f2bfu(v1);
            z0[(size_t)r * 64 + cb + 32] = f2bfu(v2);
            z0[(size_t)r * 64 + cb + 48] = 0;
            y0[(size_t)r * 64 + cb] = f2bfu(dc * v0);
            y0[(size_t)r * 64 + cb + 16] = f2bfu(dc * v1);
            y0[(size_t)r * 64 + cb + 32] = f2bfu(dc * v2);
            y0[(size_t)r * 64 + cb + 48] = 0;
        }
    }
}

__global__ void count_kernel(const int* __restrict__ eidx, int* __restrict__ counts) {
    int e = blockIdx.x * 256 + threadIdx.x;
    if (e < EE) atomicAdd(&counts[eidx[EE + e]], 1);
}

__global__ void scan1(const int* __restrict__ counts, int* __restrict__ ptr,
                      int* __restrict__ bsum) {
    __shared__ int s[256];
    int tid = threadIdx.x;
    int i = blockIdx.x * 256 + tid;
    int v = (i < NN) ? counts[i] : 0;
    s[tid] = v;
    __syncthreads();
    for (int off = 1; off < 256; off <<= 1) {
        int t = (tid >= off) ? s[tid - off] : 0;
        __syncthreads();
        s[tid] += t;
        __syncthreads();
    }
    if (i < NN) ptr[i] = s[tid] - v;
    if (tid == 255) bsum[blockIdx.x] = s[255];
}

__global__ void scan2(int* __restrict__ bsum) {
    __shared__ int s[512];
    int tid = threadIdx.x;
    int v = (tid < 391) ? bsum[tid] : 0;
    s[tid] = v;
    __syncthreads();
    for (int off = 1; off < 512; off <<= 1) {
        int t = (tid >= off) ? s[tid - off] : 0;
        __syncthreads();
        s[tid] += t;
        __syncthreads();
    }
    if (tid < 391) bsum[tid] = s[tid] - v;
}

__global__ void scan3(int* __restrict__ ptr, const int* __restrict__ bsum,
                      const int* __restrict__ counts, float* __restrict__ dinvp,
                      int* __restrict__ ptr2) {
    int i = blockIdx.x * 256 + threadIdx.x;
    if (i < NN) {
        int p = ptr[i] + bsum[blockIdx.x];
        ptr[i] = p;
        ptr2[i] = p;
        dinvp[i] = rsqrtf(1.0f + (float)counts[i]);
    }
    if (i == 0) { ptr[NN] = EE; ptr2[NN] = EE; }
}

// bucket edges by target: crow[pos] = source row only (no weight — y-state absorbs dinv[r])
__global__ void scatter_kernel(const int* __restrict__ eidx, int* __restrict__ ptr2,
                               int* __restrict__ crow) {
    int e = blockIdx.x * 256 + threadIdx.x;
    if (e < EE) {
        int r = eidx[e];
        int c = eidx[EE + e];
        int pos = atomicAdd(&ptr2[c], 1);
        crow[pos] = r;
    }
}

// 2 nodes per wave; branch-free chunks of 8 edges per node (mask = pad row NN),
// plain adds (weights folded into y-state), 16 gathers in flight.
__global__ __launch_bounds__(256, 8) void propagate(const unsigned short* __restrict__ ycur,
                                                    const unsigned short* __restrict__ z0q,
                                                    unsigned short* __restrict__ ynb,
                                                    float* __restrict__ outf,
                                                    const int* __restrict__ ptr,
                                                    const int* __restrict__ crow,
                                                    const float* __restrict__ dinvp,
                                                    const float* __restrict__ b2, int last) {
    const int lane = threadIdx.x & 63;
    const int wid = blockIdx.x * 4 + (threadIdx.x >> 6);
    const int n0 = wid, n1 = wid + HALFN;

    int beg0 = __builtin_amdgcn_readfirstlane(ptr[n0]);
    int end0 = __builtin_amdgcn_readfirstlane(ptr[n0 + 1]);
    int beg1 = __builtin_amdgcn_readfirstlane(ptr[n1]);
    int end1 = __builtin_amdgcn_readfirstlane(ptr[n1 + 1]);
    const float dc0 = dinvp[n0], dc1 = dinvp[n1];

    int m0 = end0 - beg0; if (m0 > 64) m0 = 64;
    int m1 = end1 - beg1; if (m1 > 64) m1 = 64;

    // batch row loads; lanes >= m point at the zero pad-row NN
    int idx0 = beg0 + (lane < m0 ? lane : m0 - 1); if (idx0 < 0) idx0 = 0;
    int idx1 = beg1 + (lane < m1 ? lane : m1 - 1); if (idx1 < 0) idx1 = 0;
    int r0v = crow[idx0];
    int r1v = crow[idx1];
    if (lane >= m0) r0v = NN;
    if (lane >= m1) r1v = NN;

    // self-loop term = y[c]
    float A0 = bf2f(ycur[(unsigned)(n0 * 64 + lane)]), B0 = 0.f;
    float A1 = bf2f(ycur[(unsigned)(n1 * 64 + lane)]), B1 = 0.f;
    const float z00 = bf2f(z0q[(unsigned)(n0 * 64 + lane)]);
    const float z01 = bf2f(z0q[(unsigned)(n1 * 64 + lane)]);

    int nc0 = (m0 + 7) >> 3, nc1 = (m1 + 7) >> 3;
    int nc = nc0 > nc1 ? nc0 : nc1;
    for (int c = 0; c < nc; ++c) {
        const int j = c * 8;
        float x[8], y[8];
#pragma unroll
        for (int k = 0; k < 8; ++k) {
            unsigned r0 = (unsigned)__builtin_amdgcn_readlane(r0v, j + k);
            unsigned r1 = (unsigned)__builtin_amdgcn_readlane(r1v, j + k);
            x[k] = bf2f(ycur[(r0 << 6) + lane]);
            y[k] = bf2f(ycur[(r1 << 6) + lane]);
        }
#pragma unroll
        for (int k = 0; k < 8; ++k) {
            if (k & 1) { B0 += x[k]; B1 += y[k]; }
            else       { A0 += x[k]; A1 += y[k]; }
        }
    }

    // ultra-rare tail: degree > 64
    for (int e = beg0 + 64; e < end0; ++e)
        A0 += bf2f(ycur[((unsigned)crow[e] << 6) + lane]);
    for (int e = beg1 + 64; e < end1; ++e)
        A1 += bf2f(ycur[((unsigned)crow[e] << 6) + lane]);

    float rz0 = fmaf(0.5f * dc0, A0 + B0, 0.5f * z00);
    float rz1 = fmaf(0.5f * dc1, A1 + B1, 0.5f * z01);
    if (last) {
        if (lane < 40) {
            outf[(unsigned)(n0 * 40 + lane)] = rz0 + b2[lane];
            outf[(unsigned)(n1 * 40 + lane)] = rz1 + b2[lane];
        }
    } else {
        ynb[(unsigned)(n0 * 64 + lane)] = f2bfu(dc0 * rz0);
        ynb[(unsigned)(n1 * 64 + lane)] = f2bfu(dc1 * rz1);
    }
}

extern "C" void kernel_launch(void* const* d_in, const int* in_sizes, int n_in,
                              void* d_out, int out_size, void* d_ws, size_t ws_size,
                              hipStream_t stream) {
    const float* x  = (const float*)d_in[0];
    const int*   ei = (const int*)d_in[1];
    const float* W1 = (const float*)d_in[2];
    const float* b1 = (const float*)d_in[3];
    const float* W2 = (const float*)d_in[4];
    const float* b2 = (const float*)d_in[5];
    float* out = (float*)d_out;

    char* ws = (char*)d_ws;
    short*          WcT  = (short*)(ws + 0);
    float*          bc   = (float*)(ws + 49152);
    unsigned short* z0   = (unsigned short*)(ws + 65536);
    unsigned short* ya   = (unsigned short*)(ws + 12865536);
    unsigned short* yb   = (unsigned short*)(ws + 25678592);
    float*          dinv = (float*)(ws + 38491648);
    int*            cnt  = (int*)(ws + 38891648);
    int*            ptr  = (int*)(ws + 39291648);
    int*            bsum = (int*)(ws + 39691776);
    int*            ptr2 = (int*)(ws + 39693824);
    int*            crow = (int*)(ws + 40093952);

    hipMemsetAsync(cnt, 0, NN * sizeof(int), stream);
    wct_kernel<<<97, 256, 0, stream>>>(W1, W2, b1, WcT, bc);
    padzero_kernel<<<1, 128, 0, stream>>>(ya, yb);
    count_kernel<<<(EE + 255) / 256, 256, 0, stream>>>(ei, cnt);
    scan1<<<391, 256, 0, stream>>>(cnt, ptr, bsum);
    scan2<<<1, 512, 0, stream>>>(bsum);
    scan3<<<391, 256, 0, stream>>>(ptr, bsum, cnt, dinv, ptr2);
    gemm_z0<<<1563, 256, 0, stream>>>(x, WcT, bc, dinv, z0, ya);
    scatter_kernel<<<(EE + 255) / 256, 256, 0, stream>>>(ei, ptr2, crow);

    propagate<<<12500, 256, 0, stream>>>(ya, z0, yb, out, ptr, crow, dinv, b2, 0);
    propagate<<<12500, 256, 0, stream>>>(yb, z0, ya, out, ptr, crow, dinv, b2, 0);
    propagate<<<12500, 256, 0, stream>>>(ya, z0, yb, out, ptr, crow, dinv, b2, 0);
    propagate<<<12500, 256, 0, stream>>>(yb, z0, ya, out, ptr, crow, dinv, b2, 0);
    propagate<<<12500, 256, 0, stream>>>(ya, z0, yb, out, ptr, crow, dinv, b2, 1);
}

// Round 13
// 401.032 us; speedup vs baseline: 1.1143x; 1.1143x over previous
//
#include <hip/hip_runtime.h>
#include <hip/hip_bf16.h>

#define NN 100000
#define EE 1600000
#define HALFN 50000

typedef __attribute__((ext_vector_type(8))) short short8;
typedef __attribute__((ext_vector_type(4))) float f32x4;

__device__ __forceinline__ unsigned short f2bfu(float f) {
    __hip_bfloat16 h = __float2bfloat16(f);
    return *reinterpret_cast<unsigned short*>(&h);
}
__device__ __forceinline__ float bf2f(unsigned short u) {
    return __uint_as_float((unsigned int)u << 16);
}

// ---------------- workspace layout (bytes) ----------------
// WCT 0 (49152) | BC 49152 | Z0 65536 (12.8e6) | YA 12865536 ((NN+1)*128)
// YB 25678592 | DINV 38491648 | CNT 38891648 | PTR 39291648 | BSUM 39691776
// PTR2 39693824 | CROW 40093952 (6.4e6) -> total ~46.5 MB
// y-state = dinv*z, rows padded to 64 bf16 = one 128B line; row NN = zeros (mask row)

__global__ void wct_kernel(const float* __restrict__ W1, const float* __restrict__ W2,
                           const float* __restrict__ b1, short* __restrict__ WcT,
                           float* __restrict__ bc) {
    int t = blockIdx.x * 256 + threadIdx.x;
    if (t < 48 * 512) {
        int j = t >> 9, k = t & 511;
        float s = 0.f;
        if (j < 40)
            for (int i = 0; i < 128; ++i) s = fmaf(W1[k * 128 + i], W2[i * 40 + j], s);
        WcT[j * 512 + k] = (short)f2bfu(s);
    } else if (t < 48 * 512 + 48) {
        int j = t - 48 * 512;
        float s = 0.f;
        if (j < 40)
            for (int i = 0; i < 128; ++i) s = fmaf(b1[i], W2[i * 40 + j], s);
        bc[j] = s;
    }
}

// zero the mask row (row NN) of both y buffers
__global__ void padzero_kernel(unsigned short* __restrict__ ya,
                               unsigned short* __restrict__ yb) {
    int t = threadIdx.x;
    if (t < 64) ya[(size_t)NN * 64 + t] = 0;
    else if (t < 128) yb[(size_t)NN * 64 + (t - 64)] = 0;
}

// z0 = bf16( x @ Wc + bc ); y0 = bf16( dinv * z0 ).  Rows padded to 64.
__global__ __launch_bounds__(256) void gemm_z0(const float* __restrict__ x,
                                               const short* __restrict__ WcT,
                                               const float* __restrict__ bc,
                                               const float* __restrict__ dinvp,
                                               unsigned short* __restrict__ z0,
                                               unsigned short* __restrict__ y0) {
    const int tid = threadIdx.x;
    const int lane = tid & 63;
    const int wave = tid >> 6;
    const int rbase = blockIdx.x * 64 + wave * 16;
    const int row = rbase + (lane & 15);
    const int kc = lane >> 4;
    const bool rok = row < NN;

    f32x4 acc0 = {0.f, 0.f, 0.f, 0.f};
    f32x4 acc1 = {0.f, 0.f, 0.f, 0.f};
    f32x4 acc2 = {0.f, 0.f, 0.f, 0.f};

    const float* xrow = x + (size_t)row * 512 + kc * 8;
    const short* bp0 = WcT + (size_t)(lane & 15) * 512 + kc * 8;
    const short* bp1 = bp0 + 16 * 512;
    const short* bp2 = bp0 + 32 * 512;

    for (int k0 = 0; k0 < 512; k0 += 32) {
        float4 p0 = {0.f, 0.f, 0.f, 0.f}, p1 = {0.f, 0.f, 0.f, 0.f};
        if (rok) {
            p0 = *reinterpret_cast<const float4*>(xrow + k0);
            p1 = *reinterpret_cast<const float4*>(xrow + k0 + 4);
        }
        short8 a;
        a[0] = (short)f2bfu(p0.x); a[1] = (short)f2bfu(p0.y);
        a[2] = (short)f2bfu(p0.z); a[3] = (short)f2bfu(p0.w);
        a[4] = (short)f2bfu(p1.x); a[5] = (short)f2bfu(p1.y);
        a[6] = (short)f2bfu(p1.z); a[7] = (short)f2bfu(p1.w);
        short8 b0 = *reinterpret_cast<const short8*>(bp0 + k0);
        short8 b1 = *reinterpret_cast<const short8*>(bp1 + k0);
        short8 b2 = *reinterpret_cast<const short8*>(bp2 + k0);
        acc0 = __builtin_amdgcn_mfma_f32_16x16x32_bf16(a, b0, acc0, 0, 0, 0);
        acc1 = __builtin_amdgcn_mfma_f32_16x16x32_bf16(a, b1, acc1, 0, 0, 0);
        acc2 = __builtin_amdgcn_mfma_f32_16x16x32_bf16(a, b2, acc2, 0, 0, 0);
    }

    const int cb = lane & 15;
    const int rr = rbase + (lane >> 4) * 4;
#pragma unroll
    for (int q = 0; q < 4; ++q) {
        int r = rr + q;
        if (r < NN) {
            float dc = dinvp[r];
            float v0 = acc0[q] + bc[cb];
            float v1 = acc1[q] + bc[cb + 16];
            float v2 = acc2[q] + bc[cb + 32];
            z0[(size_t)r * 64 + cb] = f2bfu(v0);
            z0[(size_t)r * 64 + cb + 16] = f2bfu(v1);
            z0[(size_t)r * 64 + cb + 32] = f2bfu(v2);
            z0[(size_t)r * 64 + cb + 48] = 0;
            y0[(size_t)r * 64 + cb] = f2bfu(dc * v0);
            y0[(size_t)r * 64 + cb + 16] = f2bfu(dc * v1);
            y0[(size_t)r * 64 + cb + 32] = f2bfu(dc * v2);
            y0[(size_t)r * 64 + cb + 48] = 0;
        }
    }
}

__global__ void count_kernel(const int* __restrict__ eidx, int* __restrict__ counts) {
    int e = blockIdx.x * 256 + threadIdx.x;
    if (e < EE) atomicAdd(&counts[eidx[EE + e]], 1);
}

__global__ void scan1(const int* __restrict__ counts, int* __restrict__ ptr,
                      int* __restrict__ bsum) {
    __shared__ int s[256];
    int tid = threadIdx.x;
    int i = blockIdx.x * 256 + tid;
    int v = (i < NN) ? counts[i] : 0;
    s[tid] = v;
    __syncthreads();
    for (int off = 1; off < 256; off <<= 1) {
        int t = (tid >= off) ? s[tid - off] : 0;
        __syncthreads();
        s[tid] += t;
        __syncthreads();
    }
    if (i < NN) ptr[i] = s[tid] - v;
    if (tid == 255) bsum[blockIdx.x] = s[255];
}

__global__ void scan2(int* __restrict__ bsum) {
    __shared__ int s[512];
    int tid = threadIdx.x;
    int v = (tid < 391) ? bsum[tid] : 0;
    s[tid] = v;
    __syncthreads();
    for (int off = 1; off < 512; off <<= 1) {
        int t = (tid >= off) ? s[tid - off] : 0;
        __syncthreads();
        s[tid] += t;
        __syncthreads();
    }
    if (tid < 391) bsum[tid] = s[tid] - v;
}

__global__ void scan3(int* __restrict__ ptr, const int* __restrict__ bsum,
                      const int* __restrict__ counts, float* __restrict__ dinvp,
                      int* __restrict__ ptr2) {
    int i = blockIdx.x * 256 + threadIdx.x;
    if (i < NN) {
        int p = ptr[i] + bsum[blockIdx.x];
        ptr[i] = p;
        ptr2[i] = p;
        dinvp[i] = rsqrtf(1.0f + (float)counts[i]);
    }
    if (i == 0) { ptr[NN] = EE; ptr2[NN] = EE; }
}

// bucket edges by target, 4 edges/thread: 4 independent atomic chains in flight
__global__ void scatter_kernel(const int* __restrict__ eidx, int* __restrict__ ptr2,
                               int* __restrict__ crow) {
    const int base = blockIdx.x * 1024 + threadIdx.x;
    int e0 = base;
    int e1 = base + 256;
    int e2 = base + 512;
    int e3 = base + 768;
    // EE = 1600000 = 1562.5 * 1024: last block's e2/e3 run off -> guard each
    int r0 = 0, r1 = 0, r2 = 0, r3 = 0, c0 = 0, c1 = 0, c2 = 0, c3 = 0;
    bool v0 = e0 < EE, v1 = e1 < EE, v2 = e2 < EE, v3 = e3 < EE;
    if (v0) { r0 = eidx[e0]; c0 = eidx[EE + e0]; }
    if (v1) { r1 = eidx[e1]; c1 = eidx[EE + e1]; }
    if (v2) { r2 = eidx[e2]; c2 = eidx[EE + e2]; }
    if (v3) { r3 = eidx[e3]; c3 = eidx[EE + e3]; }
    int p0 = 0, p1 = 0, p2 = 0, p3 = 0;
    if (v0) p0 = atomicAdd(&ptr2[c0], 1);
    if (v1) p1 = atomicAdd(&ptr2[c1], 1);
    if (v2) p2 = atomicAdd(&ptr2[c2], 1);
    if (v3) p3 = atomicAdd(&ptr2[c3], 1);
    if (v0) crow[p0] = r0;
    if (v1) crow[p1] = r1;
    if (v2) crow[p2] = r2;
    if (v3) crow[p3] = r3;
}

// 2 nodes per wave; branch-free chunks of 8 edges per node (mask = pad row NN),
// plain adds (weights folded into y-state), 16 gathers in flight.
__global__ __launch_bounds__(256, 8) void propagate(const unsigned short* __restrict__ ycur,
                                                    const unsigned short* __restrict__ z0q,
                                                    unsigned short* __restrict__ ynb,
                                                    float* __restrict__ outf,
                                                    const int* __restrict__ ptr,
                                                    const int* __restrict__ crow,
                                                    const float* __restrict__ dinvp,
                                                    const float* __restrict__ b2, int last) {
    const int lane = threadIdx.x & 63;
    const int wid = blockIdx.x * 4 + (threadIdx.x >> 6);
    const int n0 = wid, n1 = wid + HALFN;

    int beg0 = __builtin_amdgcn_readfirstlane(ptr[n0]);
    int end0 = __builtin_amdgcn_readfirstlane(ptr[n0 + 1]);
    int beg1 = __builtin_amdgcn_readfirstlane(ptr[n1]);
    int end1 = __builtin_amdgcn_readfirstlane(ptr[n1 + 1]);
    const float dc0 = dinvp[n0], dc1 = dinvp[n1];

    int m0 = end0 - beg0; if (m0 > 64) m0 = 64;
    int m1 = end1 - beg1; if (m1 > 64) m1 = 64;

    // batch row loads; lanes >= m point at the zero pad-row NN
    int idx0 = beg0 + (lane < m0 ? lane : m0 - 1); if (idx0 < 0) idx0 = 0;
    int idx1 = beg1 + (lane < m1 ? lane : m1 - 1); if (idx1 < 0) idx1 = 0;
    int r0v = crow[idx0];
    int r1v = crow[idx1];
    if (lane >= m0) r0v = NN;
    if (lane >= m1) r1v = NN;

    // self-loop term = y[c]
    float A0 = bf2f(ycur[(unsigned)(n0 * 64 + lane)]), B0 = 0.f;
    float A1 = bf2f(ycur[(unsigned)(n1 * 64 + lane)]), B1 = 0.f;
    const float z00 = bf2f(z0q[(unsigned)(n0 * 64 + lane)]);
    const float z01 = bf2f(z0q[(unsigned)(n1 * 64 + lane)]);

    int nc0 = (m0 + 7) >> 3, nc1 = (m1 + 7) >> 3;
    int nc = nc0 > nc1 ? nc0 : nc1;
    for (int c = 0; c < nc; ++c) {
        const int j = c * 8;
        float x[8], y[8];
#pragma unroll
        for (int k = 0; k < 8; ++k) {
            unsigned r0 = (unsigned)__builtin_amdgcn_readlane(r0v, j + k);
            unsigned r1 = (unsigned)__builtin_amdgcn_readlane(r1v, j + k);
            x[k] = bf2f(ycur[(r0 << 6) + lane]);
            y[k] = bf2f(ycur[(r1 << 6) + lane]);
        }
#pragma unroll
        for (int k = 0; k < 8; ++k) {
            if (k & 1) { B0 += x[k]; B1 += y[k]; }
            else       { A0 += x[k]; A1 += y[k]; }
        }
    }

    // ultra-rare tail: degree > 64
    for (int e = beg0 + 64; e < end0; ++e)
        A0 += bf2f(ycur[((unsigned)crow[e] << 6) + lane]);
    for (int e = beg1 + 64; e < end1; ++e)
        A1 += bf2f(ycur[((unsigned)crow[e] << 6) + lane]);

    float rz0 = fmaf(0.5f * dc0, A0 + B0, 0.5f * z00);
    float rz1 = fmaf(0.5f * dc1, A1 + B1, 0.5f * z01);
    if (last) {
        if (lane < 40) {
            outf[(unsigned)(n0 * 40 + lane)] = rz0 + b2[lane];
            outf[(unsigned)(n1 * 40 + lane)] = rz1 + b2[lane];
        }
    } else {
        ynb[(unsigned)(n0 * 64 + lane)] = f2bfu(dc0 * rz0);
        ynb[(unsigned)(n1 * 64 + lane)] = f2bfu(dc1 * rz1);
    }
}

extern "C" void kernel_launch(void* const* d_in, const int* in_sizes, int n_in,
                              void* d_out, int out_size, void* d_ws, size_t ws_size,
                              hipStream_t stream) {
    const float* x  = (const float*)d_in[0];
    const int*   ei = (const int*)d_in[1];
    const float* W1 = (const float*)d_in[2];
    const float* b1 = (const float*)d_in[3];
    const float* W2 = (const float*)d_in[4];
    const float* b2 = (const float*)d_in[5];
    float* out = (float*)d_out;

    char* ws = (char*)d_ws;
    short*          WcT  = (short*)(ws + 0);
    float*          bc   = (float*)(ws + 49152);
    unsigned short* z0   = (unsigned short*)(ws + 65536);
    unsigned short* ya   = (unsigned short*)(ws + 12865536);
    unsigned short* yb   = (unsigned short*)(ws + 25678592);
    float*          dinv = (float*)(ws + 38491648);
    int*            cnt  = (int*)(ws + 38891648);
    int*            ptr  = (int*)(ws + 39291648);
    int*            bsum = (int*)(ws + 39691776);
    int*            ptr2 = (int*)(ws + 39693824);
    int*            crow = (int*)(ws + 40093952);

    hipMemsetAsync(cnt, 0, NN * sizeof(int), stream);
    wct_kernel<<<97, 256, 0, stream>>>(W1, W2, b1, WcT, bc);
    padzero_kernel<<<1, 128, 0, stream>>>(ya, yb);
    count_kernel<<<(EE + 255) / 256, 256, 0, stream>>>(ei, cnt);
    scan1<<<391, 256, 0, stream>>>(cnt, ptr, bsum);
    scan2<<<1, 512, 0, stream>>>(bsum);
    scan3<<<391, 256, 0, stream>>>(ptr, bsum, cnt, dinv, ptr2);
    gemm_z0<<<1563, 256, 0, stream>>>(x, WcT, bc, dinv, z0, ya);
    scatter_kernel<<<(EE + 1023) / 1024, 256, 0, stream>>>(ei, ptr2, crow);

    propagate<<<12500, 256, 0, stream>>>(ya, z0, yb, out, ptr, crow, dinv, b2, 0);
    propagate<<<12500, 256, 0, stream>>>(yb, z0, ya, out, ptr, crow, dinv, b2, 0);
    propagate<<<12500, 256, 0, stream>>>(ya, z0, yb, out, ptr, crow, dinv, b2, 0);
    propagate<<<12500, 256, 0, stream>>>(yb, z0, ya, out, ptr, crow, dinv, b2, 0);
    propagate<<<12500, 256, 0, stream>>>(ya, z0, yb, out, ptr, crow, dinv, b2, 1);
}